// Round 1
// baseline (503.716 us; speedup 1.0000x reference)
//
#include <hip/hip_runtime.h>
#include <math.h>

#define NB 8
#define NS 4
#define NP 4096
#define HID 4096
#define NHQ 32
#define NHKV 8
#define ND 128
#define NGROUP 4
#define NBS 32      /* NB*NS rows */
#define NQI 16      /* NGROUP*NS q-rows per (b,kv) */
#define NCHUNK 9
#define TCHUNK 512
#define LOG2E 1.4426950408889634f

// ---------------- transpose x (32 x 4096) -> xT (4096 x 32) ----------------
__global__ __launch_bounds__(256) void prep_xT(const float* __restrict__ x,
                                               float* __restrict__ xT) {
  int n = blockIdx.x * 256 + threadIdx.x;           // n < 131072
  int r = n >> 12;                                   // row (b*4+s)
  int k = n & 4095;
  xT[k * NBS + r] = x[n];
}

// ---------------- RoPE: q -> q_t[(b,kv)][d][i], k_new -> [(b,kv)][s][d] ----
__global__ __launch_bounds__(256) void rope_kernel(
    const float* __restrict__ qb, const float* __restrict__ kb,
    const float* __restrict__ cosp, const float* __restrict__ sinp,
    const int* __restrict__ past_len, float* __restrict__ q_t,
    float* __restrict__ k_new) {
  int n = blockIdx.x * 256 + threadIdx.x;
  int pl = past_len[0];
  if (n < NBS * HID) {  // q element
    int r = n >> 12;    // b*4+s
    int hd = n & 4095;
    int h = hd >> 7, d = hd & 127;
    int b = r >> 2, s = r & 3;
    int pos = pl + s;
    float c = cosp[pos * ND + d], sn = sinp[pos * ND + d];
    float v = qb[n];
    float other = (d < 64) ? -qb[n + 64] : qb[n - 64];
    float rv = fmaf(v, c, other * sn);
    int kv = h >> 2, g = h & 3;
    q_t[(((b * NHKV + kv) * ND + d) * NQI) + g * NS + s] = rv;
  } else {  // k element
    n -= NBS * HID;     // n < 32768
    int r = n >> 10;
    int hd = n & 1023;
    int kv = hd >> 7, d = hd & 127;
    int b = r >> 2, s = r & 3;
    int pos = pl + s;
    float c = cosp[pos * ND + d], sn = sinp[pos * ND + d];
    float v = kb[n];
    float other = (d < 64) ? -kb[n + 64] : kb[n - 64];
    k_new[((b * NHKV + kv) * NS + s) * ND + d] = fmaf(v, c, other * sn);
  }
}

// ---------------- GEMM: C[32][N] += A_T[4096][32] x W[4096][N] -------------
// mode 0: fused qkv (cb<64 -> wq, <80 -> wk, else wv). mode 1: wo -> out.
// grid.x = col-block (64 cols), grid.y = k-block (512 k), 4 waves split k.
__global__ __launch_bounds__(256) void gemm32(
    const float* __restrict__ xT, const float* __restrict__ wq,
    const float* __restrict__ wk, const float* __restrict__ wv,
    const float* __restrict__ wo, float* __restrict__ qb,
    float* __restrict__ kb2, float* __restrict__ vb, float* __restrict__ outp,
    int mode) {
  __shared__ float accl[4][64][33];  // padded: conflict-free
  int cb = blockIdx.x, kblk = blockIdx.y;
  const float* __restrict__ W;
  float* ob;
  int ld, col0;
  if (mode) {
    W = wo; ld = 4096; ob = outp; col0 = cb * 64;
  } else if (cb < 64) {
    W = wq; ld = 4096; ob = qb; col0 = cb * 64;
  } else if (cb < 80) {
    W = wk; ld = 1024; ob = kb2; col0 = (cb - 64) * 64;
  } else {
    W = wv; ld = 1024; ob = vb; col0 = (cb - 80) * 64;
  }
  int tid = threadIdx.x;
  int lane = tid & 63;
  int wid = __builtin_amdgcn_readfirstlane(tid >> 6);
  int k0 = kblk * 512 + wid * 128;
  const float* wp = W + (size_t)k0 * ld + col0 + lane;
  const float* xp = xT + (size_t)k0 * NBS;
  float acc[NBS];
#pragma unroll
  for (int m = 0; m < NBS; m++) acc[m] = 0.f;
#pragma unroll 4
  for (int kk = 0; kk < 128; ++kk) {
    float w = wp[(size_t)kk * ld];
    const float* xr = xp + kk * NBS;  // wave-uniform address -> s_load
#pragma unroll
    for (int m = 0; m < NBS; m++) acc[m] = fmaf(xr[m], w, acc[m]);
  }
#pragma unroll
  for (int m = 0; m < NBS; m++) accl[wid][lane][m] = acc[m];
  __syncthreads();
#pragma unroll
  for (int j = 0; j < 8; j++) {
    int o = j * 256 + tid;
    int c = o & 63, m = o >> 6;
    float s = accl[0][c][m] + accl[1][c][m] + accl[2][c][m] + accl[3][c][m];
    atomicAdd(&ob[(size_t)m * ld + col0 + c], s);
  }
}

// ---------------- attention: grid = (b*8+kv)*9 + chunk ---------------------
__global__ __launch_bounds__(256) void attn_kernel(
    const float* __restrict__ q_t, const float* __restrict__ k_cache,
    const float* __restrict__ v_cache, const float* __restrict__ k_new,
    const float* __restrict__ vb, float* __restrict__ part_o,
    float* __restrict__ part_m, float* __restrict__ part_l) {
  __shared__ float p_lds[TCHUNK * 17];  // stride 17: conflict-free
  __shared__ float redm[NQI][4];
  __shared__ float redl[NQI][4];
  int blk = blockIdx.x;
  int chunk = blk % NCHUNK;
  int bk = blk / NCHUNK;
  int b = bk >> 3, kv = bk & 7;
  int tid = threadIdx.x;
  int lane = tid & 63;
  int wid = __builtin_amdgcn_readfirstlane(tid >> 6);
  bool last = (chunk == 8);
  int tcount = last ? NS : TCHUNK;
  const float* qbase = q_t + (size_t)bk * ND * NQI;  // [d][i], uniform loads
  float sc[2][NQI];
#pragma unroll
  for (int r = 0; r < 2; r++) {
    int t_loc = r * 256 + tid;
    bool valid = t_loc < tcount;
    int t_eff = valid ? t_loc : 0;
    const float* kp =
        last ? (k_new + ((size_t)bk * NS + t_eff) * ND)
             : (k_cache +
                (((size_t)b * NP + chunk * TCHUNK + t_eff) * NHKV + kv) * ND);
    float s_acc[NQI];
#pragma unroll
    for (int i = 0; i < NQI; i++) s_acc[i] = 0.f;
    for (int d4 = 0; d4 < 32; ++d4) {
      float4 kvv = *(const float4*)(kp + d4 * 4);
      const float* qp = qbase + (d4 * 4) * NQI;  // 64 consecutive, uniform
#pragma unroll
      for (int i = 0; i < NQI; i++) {
        float s = s_acc[i];
        s = fmaf(kvv.x, qp[i], s);
        s = fmaf(kvv.y, qp[NQI + i], s);
        s = fmaf(kvv.z, qp[2 * NQI + i], s);
        s = fmaf(kvv.w, qp[3 * NQI + i], s);
        s_acc[i] = s;
      }
    }
    const float scale = 0.08838834764831845f;  // 1/sqrt(128)
#pragma unroll
    for (int i = 0; i < NQI; i++) {
      float sv = s_acc[i] * scale;
      if (!valid || (last && t_loc > (i & 3))) sv = -__builtin_inff();
      sc[r][i] = sv;
    }
  }
  // block max per i
#pragma unroll
  for (int i = 0; i < NQI; i++) {
    float m = fmaxf(sc[0][i], sc[1][i]);
#pragma unroll
    for (int off = 1; off < 64; off <<= 1) m = fmaxf(m, __shfl_xor(m, off, 64));
    if (lane == 0) redm[i][wid] = m;
  }
  __syncthreads();
  float l_loc[NQI];
#pragma unroll
  for (int i = 0; i < NQI; i++) {
    float m_i = fmaxf(fmaxf(redm[i][0], redm[i][1]),
                      fmaxf(redm[i][2], redm[i][3]));
    float p0 = exp2f((sc[0][i] - m_i) * LOG2E);
    float p1 = exp2f((sc[1][i] - m_i) * LOG2E);
    p_lds[(size_t)tid * 17 + i] = p0;
    p_lds[(size_t)(256 + tid) * 17 + i] = p1;
    l_loc[i] = p0 + p1;
  }
  // block sum per i
#pragma unroll
  for (int i = 0; i < NQI; i++) {
    float l = l_loc[i];
#pragma unroll
    for (int off = 1; off < 64; off <<= 1) l += __shfl_xor(l, off, 64);
    if (lane == 0) redl[i][wid] = l;
  }
  __syncthreads();
  // PV: thread -> 2 q-rows (i0,i0+1) x 4 d
  int g8 = tid >> 5;
  int i0 = g8 * 2;
  int dq = (tid & 31) * 4;
  float o0[4] = {0, 0, 0, 0}, o1[4] = {0, 0, 0, 0};
  for (int t = 0; t < tcount; ++t) {
    const float* vp =
        last ? (vb + ((size_t)b * NS + t) * (NHKV * ND) + kv * ND)
             : (v_cache +
                (((size_t)b * NP + chunk * TCHUNK + t) * NHKV + kv) * ND);
    float4 vv = *(const float4*)(vp + dq);
    float p0 = p_lds[(size_t)t * 17 + i0];
    float p1 = p_lds[(size_t)t * 17 + i0 + 1];
    o0[0] = fmaf(p0, vv.x, o0[0]); o0[1] = fmaf(p0, vv.y, o0[1]);
    o0[2] = fmaf(p0, vv.z, o0[2]); o0[3] = fmaf(p0, vv.w, o0[3]);
    o1[0] = fmaf(p1, vv.x, o1[0]); o1[1] = fmaf(p1, vv.y, o1[1]);
    o1[2] = fmaf(p1, vv.z, o1[2]); o1[3] = fmaf(p1, vv.w, o1[3]);
  }
  size_t obase = (size_t)blk * (NQI * ND);
#pragma unroll
  for (int j = 0; j < 4; j++) {
    part_o[obase + (size_t)i0 * ND + dq + j] = o0[j];
    part_o[obase + (size_t)(i0 + 1) * ND + dq + j] = o1[j];
  }
  if (tid < NQI) {
    int i = tid;
    float m_i = fmaxf(fmaxf(redm[i][0], redm[i][1]),
                      fmaxf(redm[i][2], redm[i][3]));
    float l_i = redl[i][0] + redl[i][1] + redl[i][2] + redl[i][3];
    part_m[(size_t)blk * NQI + i] = m_i;
    part_l[(size_t)blk * NQI + i] = l_i;
  }
}

// ---------------- combine partials -> attn_T (4096 x 32) -------------------
__global__ __launch_bounds__(256) void combine_kernel(
    const float* __restrict__ part_o, const float* __restrict__ part_m,
    const float* __restrict__ part_l, float* __restrict__ attn_T) {
  int bk = blockIdx.x;
  int tid = threadIdx.x;
  int i = tid >> 4;
  int d8 = (tid & 15) * 8;
  float M = -__builtin_inff();
#pragma unroll
  for (int c = 0; c < NCHUNK; c++)
    M = fmaxf(M, part_m[((size_t)bk * NCHUNK + c) * NQI + i]);
  float L = 0.f;
  float o[8] = {0, 0, 0, 0, 0, 0, 0, 0};
#pragma unroll
  for (int c = 0; c < NCHUNK; c++) {
    size_t pc = (size_t)bk * NCHUNK + c;
    float mc = part_m[pc * NQI + i];
    float w = exp2f((mc - M) * LOG2E);
    L = fmaf(part_l[pc * NQI + i], w, L);
    const float* po = part_o + pc * (NQI * ND) + (size_t)i * ND + d8;
#pragma unroll
    for (int j = 0; j < 8; j++) o[j] = fmaf(w, po[j], o[j]);
  }
  float inv = 1.0f / L;
  int b = bk >> 3, kv = bk & 7;
  int g = i >> 2, s = i & 3;
  int h = kv * NGROUP + g;
  int r = b * NS + s;
#pragma unroll
  for (int j = 0; j < 8; j++)
    attn_T[(size_t)(h * ND + d8 + j) * NBS + r] = o[j] * inv;
}

// ---------------------------------------------------------------------------
extern "C" void kernel_launch(void* const* d_in, const int* in_sizes, int n_in,
                              void* d_out, int out_size, void* d_ws,
                              size_t ws_size, hipStream_t stream) {
  const float* x = (const float*)d_in[0];
  const float* wq = (const float*)d_in[1];
  const float* wk = (const float*)d_in[2];
  const float* wv = (const float*)d_in[3];
  const float* wo = (const float*)d_in[4];
  const float* cosp = (const float*)d_in[5];
  const float* sinp = (const float*)d_in[6];
  const float* k_cache = (const float*)d_in[7];
  const float* v_cache = (const float*)d_in[8];
  const int* past_len = (const int*)d_in[9];
  float* out = (float*)d_out;

  float* ws = (float*)d_ws;
  float* xT = ws;                      // 131072
  float* qb = xT + 131072;             // 131072
  float* kb = qb + 131072;             // 32768
  float* vb = kb + 32768;              // 32768
  float* q_t = vb + 32768;             // 131072
  float* k_new = q_t + 131072;         // 32768
  float* attn_T = k_new + 32768;       // 131072
  float* part_o = attn_T + 131072;     // 64*9*2048 = 1179648
  float* part_m = part_o + 1179648;    // 9216
  float* part_l = part_m + 9216;       // 9216

  // zero accumulation targets (re-poisoned to 0xAA before every call)
  hipMemsetAsync(qb, 0, (131072 + 32768 + 32768) * sizeof(float), stream);
  hipMemsetAsync(out, 0, (size_t)NBS * HID * sizeof(float), stream);

  prep_xT<<<512, 256, 0, stream>>>(x, xT);
  gemm32<<<dim3(96, 8), 256, 0, stream>>>(xT, wq, wk, wv, wo, qb, kb, vb, out,
                                          0);
  rope_kernel<<<640, 256, 0, stream>>>(qb, kb, cosp, sinp, past_len, q_t,
                                       k_new);
  attn_kernel<<<64 * NCHUNK, 256, 0, stream>>>(q_t, k_cache, v_cache, k_new,
                                               vb, part_o, part_m, part_l);
  combine_kernel<<<64, 256, 0, stream>>>(part_o, part_m, part_l, attn_T);
  gemm32<<<dim3(64, 8), 256, 0, stream>>>(attn_T, wq, wk, wv, wo, qb, kb, vb,
                                          out, 1);
}